// Round 10
// baseline (173.891 us; speedup 1.0000x reference)
//
#include <hip/hip_runtime.h>
#include <hip/hip_bf16.h>

#define B_ 32
#define T_ 1024
#define D_ 128
#define H_ 4
#define DH_ 32

typedef unsigned short ushort_t;
typedef unsigned short ushort4_t __attribute__((ext_vector_type(4)));
typedef unsigned short ushort8_t __attribute__((ext_vector_type(8)));
typedef short short8_t __attribute__((ext_vector_type(8)));
typedef float float4_t __attribute__((ext_vector_type(4)));

__device__ __forceinline__ float bf2f(unsigned short u) {
    union { unsigned int i; float f; } x;
    x.i = ((unsigned int)u) << 16;
    return x.f;
}
__device__ __forceinline__ ushort_t f2bf_bits(float f) {
    __hip_bfloat16 h = __float2bfloat16(f);
    return *reinterpret_cast<ushort_t*>(&h);
}

// ---- tiny transpose kernels (bf16 B-frag layouts for MFMA) ----
// Wt[n*128+k] = bf16(W[k*384+n]), n<384, k<128   (49152 elems)
__global__ __launch_bounds__(256) void transpose_w(
    const float* __restrict__ W, ushort_t* __restrict__ Wt)
{
    const int id = blockIdx.x * 256 + threadIdx.x;
    const int n = id >> 7, k = id & 127;
    Wt[id] = f2bf_bits(W[(size_t)k * 384 + n]);
}
// Wot[n*128+k] = bf16(Wo[k*128+n]), n<128, k<128  (16384 elems)
__global__ __launch_bounds__(256) void transpose_wo(
    const float* __restrict__ Wo, ushort_t* __restrict__ Wot)
{
    const int id = blockIdx.x * 256 + threadIdx.x;
    const int n = id >> 7, k = id & 127;
    Wot[id] = f2bf_bits(Wo[(size_t)k * 128 + n]);
}

// ---------------- Kernel 1: MFMA QKV projection ----------------
// Wave = 16 tokens x 192 cols (wpart = gw&1). 48 MFMAs/wave.
// q/k: direct stores. v: LDS-staged transpose -> 16B coalesced-per-lane
// stores into vt [B,H,DH,T] (was 2B stores at 2KB stride).
__global__ __launch_bounds__(256) void qkv_mfma(
    const float* __restrict__ x, const ushort_t* __restrict__ Wt,
    __hip_bfloat16* __restrict__ qws, __hip_bfloat16* __restrict__ kws,
    __hip_bfloat16* __restrict__ vtws)
{
    __shared__ ushort_t vlds[2][128 * 16]; // 8 KB; wave-private halves (wid 1,3)

    const int lane = threadIdx.x & 63;
    const int i15 = lane & 15, quad = lane >> 4;
    const int gw = blockIdx.x * 4 + (threadIdx.x >> 6); // [0, B*T/8)
    const int wpart = gw & 1;
    const int widv = threadIdx.x >> 7;                  // 0 for wid1, 1 for wid3
    const int row0 = (gw >> 1) * 16;

    // A-frags: x rows (f32 -> bf16 in-register)
    short8_t af[4];
    #pragma unroll
    for (int kc = 0; kc < 4; ++kc) {
        const float4 x0 = *(const float4*)(x + (size_t)(row0 + i15) * 128 + kc * 32 + quad * 8);
        const float4 x1 = *(const float4*)(x + (size_t)(row0 + i15) * 128 + kc * 32 + quad * 8 + 4);
        short8_t a;
        a[0] = (short)f2bf_bits(x0.x); a[1] = (short)f2bf_bits(x0.y);
        a[2] = (short)f2bf_bits(x0.z); a[3] = (short)f2bf_bits(x0.w);
        a[4] = (short)f2bf_bits(x1.x); a[5] = (short)f2bf_bits(x1.y);
        a[6] = (short)f2bf_bits(x1.z); a[7] = (short)f2bf_bits(x1.w);
        af[kc] = a;
    }

    float4_t acc[12];
    #pragma unroll
    for (int nt = 0; nt < 12; ++nt) acc[nt] = (float4_t){0.f, 0.f, 0.f, 0.f};

    #pragma unroll
    for (int nt = 0; nt < 12; ++nt) {
        const int n = wpart * 192 + nt * 16 + i15;
        const ushort_t* wb = Wt + (size_t)n * 128 + quad * 8;
        #pragma unroll
        for (int kc = 0; kc < 4; ++kc) {
            const short8_t bf = *(const short8_t*)(wb + kc * 32);
            acc[nt] = __builtin_amdgcn_mfma_f32_16x16x32_bf16(af[kc], bf, acc[nt], 0, 0, 0);
        }
    }

    const float scale = 0.17677669529663687f; // 1/sqrt(32)
    #pragma unroll
    for (int nt = 0; nt < 12; ++nt) {
        const int n = wpart * 192 + nt * 16 + i15;
        const int region = n >> 7;        // 0=q, 1=k, 2=v (uniform per nt)
        const int nsub = n & 127;
        if (region == 2) {
            // stage to LDS [ch][t]: pack 4 consecutive-t bf16 -> one b64 write
            ushort4_t pk;
            #pragma unroll
            for (int r = 0; r < 4; ++r) pk[r] = f2bf_bits(acc[nt][r]);
            *(ushort4_t*)(&vlds[widv][nsub * 16 + quad * 4]) = pk;
        } else {
            const int h = nsub >> 5, dh = nsub & 31;
            #pragma unroll
            for (int r = 0; r < 4; ++r) {
                const int m = row0 + quad * 4 + r;
                const int bb = m >> 10, t = m & 1023;
                const int bhn = bb * H_ + h;
                if (region == 0)
                    qws[((size_t)bhn * T_ + t) * DH_ + dh] = __float2bfloat16(acc[nt][r] * scale);
                else
                    kws[((size_t)bhn * T_ + t) * DH_ + dh] = __float2bfloat16(acc[nt][r]);
            }
        }
    }

    if (wpart == 1) {
        // flush vt: per lane 2 channels x (16 t = 32B) via b128 LDS reads.
        // Wave-private LDS + in-wave DS ordering -> no barrier needed.
        const int bb = row0 >> 10, t0 = row0 & 1023;
        #pragma unroll
        for (int rr = 0; rr < 2; ++rr) {
            const int ch = rr * 64 + lane;
            const int h = ch >> 5, dh = ch & 31;
            const ushort8_t a0 = *(const ushort8_t*)(&vlds[widv][ch * 16]);
            const ushort8_t a1 = *(const ushort8_t*)(&vlds[widv][ch * 16 + 8]);
            ushort_t* dst = (ushort_t*)vtws +
                ((size_t)(bb * H_ + h) * DH_ + dh) * T_ + t0;
            *(ushort8_t*)(dst) = a0;
            *(ushort8_t*)(dst + 8) = a1;
        }
    }
}

// ---------------- Kernel 2: MFMA flash attention, 64-key chunks ----------------
// 4 independent waves/block (no barriers); wave owns 16 queries of one (b,h).
// Per 64-key chunk: 4 QK MFMAs, exp (no-max: scores bounded ~|s|<2), P via
// padded wave-private LDS (stride 72 shorts kills the 16-way read conflict),
// 4 PV MFMAs against transposed V. Heavy tiles first.
__global__ __launch_bounds__(256) void attn_mfma(
    const ushort_t* __restrict__ qws, const ushort_t* __restrict__ kws,
    const ushort_t* __restrict__ vtws, const int* __restrict__ keys_length,
    __hip_bfloat16* __restrict__ attn_out)
{
    __shared__ ushort_t plds_all[4][16 * 72]; // 4 x 2304 B, wave-private

    const int wid = threadIdx.x >> 6;
    ushort_t* plds = plds_all[wid];
    const int lane = threadIdx.x & 63;
    const int i15 = lane & 15, quad = lane >> 4;
    const int wg = blockIdx.x * 4 + wid;
    const int g = wg & 63;
    const int bh = wg >> 6;
    const int b = bh >> 2, h = bh & 3;
    const int qt = 63 - g;            // heavy tiles first
    const int qbase = qt * 16;
    const int len = keys_length[b];

    const ushort_t* Qb = qws + (size_t)bh * T_ * DH_;
    const ushort_t* Kb = kws + (size_t)bh * T_ * DH_;
    const ushort_t* Vtb = vtws + (size_t)bh * DH_ * T_;

    const short8_t qfrag =
        *(const short8_t*)(Qb + ((size_t)(qbase + i15)) * DH_ + quad * 8);

    int limit[4];
    #pragma unroll
    for (int r = 0; r < 4; ++r)
        limit[r] = min(qbase + quad * 4 + r + 1, len);

    const int kend = min(qbase + 16, len);
    const int nch = (kend + 63) >> 6; // 64-key chunks, >= 1

    float4_t o0 = {0.f, 0.f, 0.f, 0.f}, o1 = {0.f, 0.f, 0.f, 0.f};
    float lrow[4] = {0.f, 0.f, 0.f, 0.f};
    const float4_t zero = {0.f, 0.f, 0.f, 0.f};

    for (int c = 0; c < nch; ++c) {
        const int k0 = c * 64;

        short8_t kf[4], vf[4];
        #pragma unroll
        for (int grp = 0; grp < 4; ++grp)
            kf[grp] = *(const short8_t*)(Kb + ((size_t)(k0 + grp * 16 + i15)) * DH_ + quad * 8);
        vf[0] = *(const short8_t*)(Vtb + (size_t)i15 * T_ + k0 + quad * 8);
        vf[1] = *(const short8_t*)(Vtb + (size_t)i15 * T_ + k0 + 32 + quad * 8);
        vf[2] = *(const short8_t*)(Vtb + (size_t)(16 + i15) * T_ + k0 + quad * 8);
        vf[3] = *(const short8_t*)(Vtb + (size_t)(16 + i15) * T_ + k0 + 32 + quad * 8);

        float4_t s[4];
        #pragma unroll
        for (int grp = 0; grp < 4; ++grp)
            s[grp] = __builtin_amdgcn_mfma_f32_16x16x32_bf16(qfrag, kf[grp], zero, 0, 0, 0);

        #pragma unroll
        for (int grp = 0; grp < 4; ++grp) {
            #pragma unroll
            for (int r = 0; r < 4; ++r) {
                const float p = (k0 + grp * 16 + i15 < limit[r]) ? __expf(s[grp][r]) : 0.f;
                lrow[r] += p;
                plds[(quad * 4 + r) * 72 + grp * 16 + i15] = f2bf_bits(p);
            }
        }

        const short8_t pfA = *(const short8_t*)(plds + i15 * 72 + quad * 8);
        const short8_t pfB = *(const short8_t*)(plds + i15 * 72 + 32 + quad * 8);

        o0 = __builtin_amdgcn_mfma_f32_16x16x32_bf16(pfA, vf[0], o0, 0, 0, 0);
        o0 = __builtin_amdgcn_mfma_f32_16x16x32_bf16(pfB, vf[1], o0, 0, 0, 0);
        o1 = __builtin_amdgcn_mfma_f32_16x16x32_bf16(pfA, vf[2], o1, 0, 0, 0);
        o1 = __builtin_amdgcn_mfma_f32_16x16x32_bf16(pfB, vf[3], o1, 0, 0, 0);
    }

    // finish l: reduce over the 16 lanes of each row group
    #pragma unroll
    for (int r = 0; r < 4; ++r) {
        float s = lrow[r];
        #pragma unroll
        for (int off = 1; off < 16; off <<= 1)
            s += __shfl_xor(s, off, 64);
        lrow[r] = s;
    }

    #pragma unroll
    for (int r = 0; r < 4; ++r) {
        const float inv = 1.f / lrow[r];
        const int row_g = qbase + quad * 4 + r;
        const size_t base = ((size_t)b * T_ + row_g) * D_ + h * DH_;
        attn_out[base + i15] = __float2bfloat16(o0[r] * inv);
        attn_out[base + 16 + i15] = __float2bfloat16(o1[r] * inv);
    }
}

// ---------------- Kernel 3: MFMA output proj + residual + LN ----------------
// Wave = 16 tokens x 128 cols; 32 MFMAs; LN on C-layout rows via 16-lane shfl.
__global__ __launch_bounds__(256) void proj_ln_mfma(
    const ushort_t* __restrict__ attn, const float* __restrict__ x,
    const ushort_t* __restrict__ Wot, const float* __restrict__ gamma,
    const float* __restrict__ beta, float* __restrict__ out)
{
    const int lane = threadIdx.x & 63;
    const int i15 = lane & 15, quad = lane >> 4;
    const int gw = blockIdx.x * 4 + (threadIdx.x >> 6);
    const int row0 = gw * 16;

    short8_t af[4];
    #pragma unroll
    for (int kc = 0; kc < 4; ++kc)
        af[kc] = *(const short8_t*)(attn + (size_t)(row0 + i15) * 128 + kc * 32 + quad * 8);

    float4_t acc[8];
    #pragma unroll
    for (int nt = 0; nt < 8; ++nt) acc[nt] = (float4_t){0.f, 0.f, 0.f, 0.f};

    #pragma unroll
    for (int nt = 0; nt < 8; ++nt) {
        const ushort_t* wb = Wot + (size_t)(nt * 16 + i15) * 128 + quad * 8;
        #pragma unroll
        for (int kc = 0; kc < 4; ++kc) {
            const short8_t bf = *(const short8_t*)(wb + kc * 32);
            acc[nt] = __builtin_amdgcn_mfma_f32_16x16x32_bf16(af[kc], bf, acc[nt], 0, 0, 0);
        }
    }

    float g[8], be[8];
    #pragma unroll
    for (int nt = 0; nt < 8; ++nt) {
        g[nt] = gamma[nt * 16 + i15];
        be[nt] = beta[nt * 16 + i15];
    }

    #pragma unroll
    for (int r = 0; r < 4; ++r) {
        const int m = row0 + quad * 4 + r;
        float y[8];
        float s1 = 0.f, s2 = 0.f;
        #pragma unroll
        for (int nt = 0; nt < 8; ++nt) {
            y[nt] = acc[nt][r] + x[(size_t)m * 128 + nt * 16 + i15];
            s1 += y[nt];
            s2 += y[nt] * y[nt];
        }
        #pragma unroll
        for (int off = 1; off < 16; off <<= 1) {
            s1 += __shfl_xor(s1, off, 64);
            s2 += __shfl_xor(s2, off, 64);
        }
        const float mean = s1 * (1.f / 128.f);
        const float var = s2 * (1.f / 128.f) - mean * mean;
        const float rstd = rsqrtf(var + 1e-9f);
        #pragma unroll
        for (int nt = 0; nt < 8; ++nt)
            out[(size_t)m * 128 + nt * 16 + i15] = (y[nt] - mean) * rstd * g[nt] + be[nt];
    }
}

extern "C" void kernel_launch(void* const* d_in, const int* in_sizes, int n_in,
                              void* d_out, int out_size, void* d_ws, size_t ws_size,
                              hipStream_t stream) {
    const float* x      = (const float*)d_in[0];
    const int* keys_len = (const int*)d_in[1];
    const float* W      = (const float*)d_in[2];
    const float* Wo     = (const float*)d_in[3];
    const float* gamma  = (const float*)d_in[4];
    const float* beta   = (const float*)d_in[5];
    float* out          = (float*)d_out;  // f32 output (proven round 5)

    // ws (32 MB total, proven safe): q | k | vt | attn-out, 8 MB each.
    // Wt (96 KB) lives in the attn-out segment (dead until attn runs);
    // Wot (32 KB) lives in the q segment (dead after attn).
    const size_t seg = (size_t)B_ * H_ * T_ * DH_;
    __hip_bfloat16* qws  = (__hip_bfloat16*)d_ws;
    __hip_bfloat16* kws  = qws + seg;
    __hip_bfloat16* vtws = qws + 2 * seg;
    __hip_bfloat16* aws  = qws + 3 * seg;
    ushort_t* Wt  = (ushort_t*)aws;
    ushort_t* Wot = (ushort_t*)qws;

    transpose_w<<<192, 256, 0, stream>>>(W, Wt);              // 49152 elems
    qkv_mfma<<<B_ * T_ / 32, 256, 0, stream>>>(x, Wt, qws, kws, vtws);
    attn_mfma<<<B_ * H_ * (T_ / 16) / 4, 256, 0, stream>>>(
        (const ushort_t*)qws, (const ushort_t*)kws, (const ushort_t*)vtws,
        keys_len, aws);
    transpose_wo<<<64, 256, 0, stream>>>(Wo, Wot);            // 16384 elems
    proj_ln_mfma<<<B_ * T_ / 64, 256, 0, stream>>>(
        (const ushort_t*)aws, x, Wot, gamma, beta, out);
}

// Round 11
// 165.945 us; speedup vs baseline: 1.0479x; 1.0479x over previous
//
#include <hip/hip_runtime.h>
#include <hip/hip_bf16.h>

#define B_ 32
#define T_ 1024
#define D_ 128
#define H_ 4
#define DH_ 32

typedef unsigned short ushort_t;
typedef unsigned short ushort4_t __attribute__((ext_vector_type(4)));
typedef unsigned short ushort8_t __attribute__((ext_vector_type(8)));
typedef short short8_t __attribute__((ext_vector_type(8)));
typedef float float4_t __attribute__((ext_vector_type(4)));

__device__ __forceinline__ float bf2f(unsigned short u) {
    union { unsigned int i; float f; } x;
    x.i = ((unsigned int)u) << 16;
    return x.f;
}
__device__ __forceinline__ ushort_t f2bf_bits(float f) {
    __hip_bfloat16 h = __float2bfloat16(f);
    return *reinterpret_cast<ushort_t*>(&h);
}

// ---- tiny transpose kernels (bf16 B-frag layouts for MFMA) ----
// Wt[n*128+k] = bf16(W[k*384+n]), n<384, k<128   (49152 elems)
__global__ __launch_bounds__(256) void transpose_w(
    const float* __restrict__ W, ushort_t* __restrict__ Wt)
{
    const int id = blockIdx.x * 256 + threadIdx.x;
    const int n = id >> 7, k = id & 127;
    Wt[id] = f2bf_bits(W[(size_t)k * 384 + n]);
}
// Wot[n*128+k] = bf16(Wo[k*128+n]), n<128, k<128  (16384 elems)
__global__ __launch_bounds__(256) void transpose_wo(
    const float* __restrict__ Wo, ushort_t* __restrict__ Wot)
{
    const int id = blockIdx.x * 256 + threadIdx.x;
    const int n = id >> 7, k = id & 127;
    Wot[id] = f2bf_bits(Wo[(size_t)k * 128 + n]);
}

// ---------------- Kernel 1: MFMA QKV projection ----------------
// Wave = 16 tokens x 192 cols (wpart = gw&1). 48 MFMAs/wave.
// q/k: direct stores. v: LDS-staged transpose -> 16B coalesced-per-lane
// stores into vt [B,H,DH,T].
__global__ __launch_bounds__(256) void qkv_mfma(
    const float* __restrict__ x, const ushort_t* __restrict__ Wt,
    __hip_bfloat16* __restrict__ qws, __hip_bfloat16* __restrict__ kws,
    __hip_bfloat16* __restrict__ vtws)
{
    __shared__ ushort_t vlds[2][128 * 16]; // 8 KB; wave-private halves (wid 1,3)

    const int lane = threadIdx.x & 63;
    const int i15 = lane & 15, quad = lane >> 4;
    const int gw = blockIdx.x * 4 + (threadIdx.x >> 6); // [0, B*T/8)
    const int wpart = gw & 1;
    const int widv = threadIdx.x >> 7;                  // 0 for wid1, 1 for wid3
    const int row0 = (gw >> 1) * 16;

    // A-frags: x rows (f32 -> bf16 in-register)
    short8_t af[4];
    #pragma unroll
    for (int kc = 0; kc < 4; ++kc) {
        const float4 x0 = *(const float4*)(x + (size_t)(row0 + i15) * 128 + kc * 32 + quad * 8);
        const float4 x1 = *(const float4*)(x + (size_t)(row0 + i15) * 128 + kc * 32 + quad * 8 + 4);
        short8_t a;
        a[0] = (short)f2bf_bits(x0.x); a[1] = (short)f2bf_bits(x0.y);
        a[2] = (short)f2bf_bits(x0.z); a[3] = (short)f2bf_bits(x0.w);
        a[4] = (short)f2bf_bits(x1.x); a[5] = (short)f2bf_bits(x1.y);
        a[6] = (short)f2bf_bits(x1.z); a[7] = (short)f2bf_bits(x1.w);
        af[kc] = a;
    }

    float4_t acc[12];
    #pragma unroll
    for (int nt = 0; nt < 12; ++nt) acc[nt] = (float4_t){0.f, 0.f, 0.f, 0.f};

    #pragma unroll
    for (int nt = 0; nt < 12; ++nt) {
        const int n = wpart * 192 + nt * 16 + i15;
        const ushort_t* wb = Wt + (size_t)n * 128 + quad * 8;
        #pragma unroll
        for (int kc = 0; kc < 4; ++kc) {
            const short8_t bf = *(const short8_t*)(wb + kc * 32);
            acc[nt] = __builtin_amdgcn_mfma_f32_16x16x32_bf16(af[kc], bf, acc[nt], 0, 0, 0);
        }
    }

    const float scale = 0.17677669529663687f; // 1/sqrt(32)
    #pragma unroll
    for (int nt = 0; nt < 12; ++nt) {
        const int n = wpart * 192 + nt * 16 + i15;
        const int region = n >> 7;        // 0=q, 1=k, 2=v (uniform per nt)
        const int nsub = n & 127;
        if (region == 2) {
            ushort4_t pk;
            #pragma unroll
            for (int r = 0; r < 4; ++r) pk[r] = f2bf_bits(acc[nt][r]);
            *(ushort4_t*)(&vlds[widv][nsub * 16 + quad * 4]) = pk;
        } else {
            const int h = nsub >> 5, dh = nsub & 31;
            #pragma unroll
            for (int r = 0; r < 4; ++r) {
                const int m = row0 + quad * 4 + r;
                const int bb = m >> 10, t = m & 1023;
                const int bhn = bb * H_ + h;
                if (region == 0)
                    qws[((size_t)bhn * T_ + t) * DH_ + dh] = __float2bfloat16(acc[nt][r] * scale);
                else
                    kws[((size_t)bhn * T_ + t) * DH_ + dh] = __float2bfloat16(acc[nt][r]);
            }
        }
    }

    if (wpart == 1) {
        const int bb = row0 >> 10, t0 = row0 & 1023;
        #pragma unroll
        for (int rr = 0; rr < 2; ++rr) {
            const int ch = rr * 64 + lane;
            const int h = ch >> 5, dh = ch & 31;
            const ushort8_t a0 = *(const ushort8_t*)(&vlds[widv][ch * 16]);
            const ushort8_t a1 = *(const ushort8_t*)(&vlds[widv][ch * 16 + 8]);
            ushort_t* dst = (ushort_t*)vtws +
                ((size_t)(bb * H_ + h) * DH_ + dh) * T_ + t0;
            *(ushort8_t*)(dst) = a0;
            *(ushort8_t*)(dst + 8) = a1;
        }
    }
}

// ---------------- Kernel 2: split-K MFMA flash attention ----------------
// One block per (bh, 16-query tile) = 8192 blocks x 4 waves. Wave w handles
// key-chunks c = w, w+4, ... (64 keys each): 4 QK MFMAs, exp (no-max:
// scores bounded |s|<~2), P C->A transform via wave-private padded LDS,
// 4 PV MFMAs vs transposed V. Unnormalized partials (o,l) combined in LDS.
__global__ __launch_bounds__(256) void attn_mfma(
    const ushort_t* __restrict__ qws, const ushort_t* __restrict__ kws,
    const ushort_t* __restrict__ vtws, const int* __restrict__ keys_length,
    __hip_bfloat16* __restrict__ attn_out)
{
    // 9216 B: phase 1 = 4 wave-private P tiles (16x72 shorts, stride-72 pad);
    // phase 2 (after barrier) = 4 combine slots of 576 floats (512 o + 16 l).
    __shared__ float smem[2304];

    const int wid = threadIdx.x >> 6;
    const int lane = threadIdx.x & 63;
    const int i15 = lane & 15, quad = lane >> 4;
    const int g = blockIdx.x & 63;
    const int bh = blockIdx.x >> 6;
    const int b = bh >> 2, h = bh & 3;
    const int qt = 63 - g;            // heavy tiles first
    const int qbase = qt * 16;
    const int len = keys_length[b];

    const ushort_t* Qb = qws + (size_t)bh * T_ * DH_;
    const ushort_t* Kb = kws + (size_t)bh * T_ * DH_;
    const ushort_t* Vtb = vtws + (size_t)bh * DH_ * T_;

    const short8_t qfrag =
        *(const short8_t*)(Qb + ((size_t)(qbase + i15)) * DH_ + quad * 8);

    int limit[4];
    #pragma unroll
    for (int r = 0; r < 4; ++r)
        limit[r] = min(qbase + quad * 4 + r + 1, len);

    const int kend = min(qbase + 16, len);
    const int nch = (kend + 63) >> 6; // 64-key chunks, 1..16

    ushort_t* plds = (ushort_t*)(smem + wid * 576);

    float4_t o0 = {0.f, 0.f, 0.f, 0.f}, o1 = {0.f, 0.f, 0.f, 0.f};
    float lrow[4] = {0.f, 0.f, 0.f, 0.f};
    const float4_t zero = {0.f, 0.f, 0.f, 0.f};

    for (int c = wid; c < nch; c += 4) {
        const int k0 = c * 64;

        short8_t kf[4], vf[4];
        #pragma unroll
        for (int grp = 0; grp < 4; ++grp)
            kf[grp] = *(const short8_t*)(Kb + ((size_t)(k0 + grp * 16 + i15)) * DH_ + quad * 8);
        vf[0] = *(const short8_t*)(Vtb + (size_t)i15 * T_ + k0 + quad * 8);
        vf[1] = *(const short8_t*)(Vtb + (size_t)i15 * T_ + k0 + 32 + quad * 8);
        vf[2] = *(const short8_t*)(Vtb + (size_t)(16 + i15) * T_ + k0 + quad * 8);
        vf[3] = *(const short8_t*)(Vtb + (size_t)(16 + i15) * T_ + k0 + 32 + quad * 8);

        float4_t s[4];
        #pragma unroll
        for (int grp = 0; grp < 4; ++grp)
            s[grp] = __builtin_amdgcn_mfma_f32_16x16x32_bf16(qfrag, kf[grp], zero, 0, 0, 0);

        #pragma unroll
        for (int grp = 0; grp < 4; ++grp) {
            #pragma unroll
            for (int r = 0; r < 4; ++r) {
                const float p = (k0 + grp * 16 + i15 < limit[r]) ? __expf(s[grp][r]) : 0.f;
                lrow[r] += p;
                plds[(quad * 4 + r) * 72 + grp * 16 + i15] = f2bf_bits(p);
            }
        }

        const short8_t pfA = *(const short8_t*)(plds + i15 * 72 + quad * 8);
        const short8_t pfB = *(const short8_t*)(plds + i15 * 72 + 32 + quad * 8);

        o0 = __builtin_amdgcn_mfma_f32_16x16x32_bf16(pfA, vf[0], o0, 0, 0, 0);
        o0 = __builtin_amdgcn_mfma_f32_16x16x32_bf16(pfB, vf[1], o0, 0, 0, 0);
        o1 = __builtin_amdgcn_mfma_f32_16x16x32_bf16(pfA, vf[2], o1, 0, 0, 0);
        o1 = __builtin_amdgcn_mfma_f32_16x16x32_bf16(pfB, vf[3], o1, 0, 0, 0);
    }

    // l: reduce each row over its 16-lane group (stays in-wave)
    #pragma unroll
    for (int r = 0; r < 4; ++r) {
        float s = lrow[r];
        #pragma unroll
        for (int off = 1; off < 16; off <<= 1)
            s += __shfl_xor(s, off, 64);
        lrow[r] = s;
    }

    __syncthreads(); // all P-tile use done; smem becomes combine buffer

    float* comb = smem + wid * 576;
    #pragma unroll
    for (int r = 0; r < 4; ++r) {
        comb[(quad * 4 + r) * 32 + i15] = o0[r];
        comb[(quad * 4 + r) * 32 + 16 + i15] = o1[r];
    }
    if (i15 == 0) {
        #pragma unroll
        for (int r = 0; r < 4; ++r)
            comb[512 + quad * 4 + r] = lrow[r];
    }
    __syncthreads();

    // combine 4 wave-partials, normalize, write bf16 [B,T,128]
    #pragma unroll
    for (int e = threadIdx.x; e < 512; e += 256) {
        const int row = e >> 5, col = e & 31;
        const float osum = smem[e] + smem[576 + e] + smem[1152 + e] + smem[1728 + e];
        const float lsum = smem[512 + row] + smem[1088 + row] +
                           smem[1664 + row] + smem[2240 + row];
        attn_out[((size_t)b * T_ + qbase + row) * D_ + h * DH_ + col] =
            __float2bfloat16(osum / lsum);
    }
}

// ---------------- Kernel 3: MFMA output proj + residual + LN ----------------
// Wave = 16 tokens x 128 cols; 32 MFMAs; LN on C-layout rows via 16-lane shfl.
__global__ __launch_bounds__(256) void proj_ln_mfma(
    const ushort_t* __restrict__ attn, const float* __restrict__ x,
    const ushort_t* __restrict__ Wot, const float* __restrict__ gamma,
    const float* __restrict__ beta, float* __restrict__ out)
{
    const int lane = threadIdx.x & 63;
    const int i15 = lane & 15, quad = lane >> 4;
    const int gw = blockIdx.x * 4 + (threadIdx.x >> 6);
    const int row0 = gw * 16;

    short8_t af[4];
    #pragma unroll
    for (int kc = 0; kc < 4; ++kc)
        af[kc] = *(const short8_t*)(attn + (size_t)(row0 + i15) * 128 + kc * 32 + quad * 8);

    float4_t acc[8];
    #pragma unroll
    for (int nt = 0; nt < 8; ++nt) acc[nt] = (float4_t){0.f, 0.f, 0.f, 0.f};

    #pragma unroll
    for (int nt = 0; nt < 8; ++nt) {
        const ushort_t* wb = Wot + (size_t)(nt * 16 + i15) * 128 + quad * 8;
        #pragma unroll
        for (int kc = 0; kc < 4; ++kc) {
            const short8_t bf = *(const short8_t*)(wb + kc * 32);
            acc[nt] = __builtin_amdgcn_mfma_f32_16x16x32_bf16(af[kc], bf, acc[nt], 0, 0, 0);
        }
    }

    float g[8], be[8];
    #pragma unroll
    for (int nt = 0; nt < 8; ++nt) {
        g[nt] = gamma[nt * 16 + i15];
        be[nt] = beta[nt * 16 + i15];
    }

    #pragma unroll
    for (int r = 0; r < 4; ++r) {
        const int m = row0 + quad * 4 + r;
        float y[8];
        float s1 = 0.f, s2 = 0.f;
        #pragma unroll
        for (int nt = 0; nt < 8; ++nt) {
            y[nt] = acc[nt][r] + x[(size_t)m * 128 + nt * 16 + i15];
            s1 += y[nt];
            s2 += y[nt] * y[nt];
        }
        #pragma unroll
        for (int off = 1; off < 16; off <<= 1) {
            s1 += __shfl_xor(s1, off, 64);
            s2 += __shfl_xor(s2, off, 64);
        }
        const float mean = s1 * (1.f / 128.f);
        const float var = s2 * (1.f / 128.f) - mean * mean;
        const float rstd = rsqrtf(var + 1e-9f);
        #pragma unroll
        for (int nt = 0; nt < 8; ++nt)
            out[(size_t)m * 128 + nt * 16 + i15] = (y[nt] - mean) * rstd * g[nt] + be[nt];
    }
}

extern "C" void kernel_launch(void* const* d_in, const int* in_sizes, int n_in,
                              void* d_out, int out_size, void* d_ws, size_t ws_size,
                              hipStream_t stream) {
    const float* x      = (const float*)d_in[0];
    const int* keys_len = (const int*)d_in[1];
    const float* W      = (const float*)d_in[2];
    const float* Wo     = (const float*)d_in[3];
    const float* gamma  = (const float*)d_in[4];
    const float* beta   = (const float*)d_in[5];
    float* out          = (float*)d_out;  // f32 output (proven round 5)

    // ws (32 MB total, proven safe): q | k | vt | attn-out, 8 MB each.
    // Wt (96 KB) lives in the attn-out segment (dead until attn runs);
    // Wot (32 KB) lives in the q segment (dead after attn).
    const size_t seg = (size_t)B_ * H_ * T_ * DH_;
    __hip_bfloat16* qws  = (__hip_bfloat16*)d_ws;
    __hip_bfloat16* kws  = qws + seg;
    __hip_bfloat16* vtws = qws + 2 * seg;
    __hip_bfloat16* aws  = qws + 3 * seg;
    ushort_t* Wt  = (ushort_t*)aws;
    ushort_t* Wot = (ushort_t*)qws;

    transpose_w<<<192, 256, 0, stream>>>(W, Wt);              // 49152 elems
    qkv_mfma<<<B_ * T_ / 32, 256, 0, stream>>>(x, Wt, qws, kws, vtws);
    attn_mfma<<<B_ * H_ * (T_ / 16), 256, 0, stream>>>(
        (const ushort_t*)qws, (const ushort_t*)kws, (const ushort_t*)vtws,
        keys_len, aws);
    transpose_wo<<<64, 256, 0, stream>>>(Wo, Wot);            // 16384 elems
    proj_ln_mfma<<<B_ * T_ / 64, 256, 0, stream>>>(
        (const ushort_t*)aws, x, Wot, gamma, beta, out);
}

// Round 12
// 162.377 us; speedup vs baseline: 1.0709x; 1.0220x over previous
//
#include <hip/hip_runtime.h>
#include <hip/hip_bf16.h>

#define B_ 32
#define T_ 1024
#define D_ 128
#define H_ 4
#define DH_ 32

typedef unsigned short ushort_t;
typedef unsigned short ushort4_t __attribute__((ext_vector_type(4)));
typedef unsigned short ushort8_t __attribute__((ext_vector_type(8)));
typedef short short8_t __attribute__((ext_vector_type(8)));
typedef float float4_t __attribute__((ext_vector_type(4)));

__device__ __forceinline__ ushort_t f2bf_bits(float f) {
    __hip_bfloat16 h = __float2bfloat16(f);
    return *reinterpret_cast<ushort_t*>(&h);
}
__device__ __forceinline__ ushort_t f2bf_trunc(float f) {
    union { float f; unsigned int i; } u; u.f = f;
    return (ushort_t)(u.i >> 16);
}

// ---- tiny transpose kernels (bf16 B-frag layouts for MFMA) ----
__global__ __launch_bounds__(256) void transpose_w(
    const float* __restrict__ W, ushort_t* __restrict__ Wt)
{
    const int id = blockIdx.x * 256 + threadIdx.x;
    const int n = id >> 7, k = id & 127;
    Wt[id] = f2bf_bits(W[(size_t)k * 384 + n]);
}
__global__ __launch_bounds__(256) void transpose_wo(
    const float* __restrict__ Wo, ushort_t* __restrict__ Wot)
{
    const int id = blockIdx.x * 256 + threadIdx.x;
    const int n = id >> 7, k = id & 127;
    Wot[id] = f2bf_bits(Wo[(size_t)k * 128 + n]);
}

// ---------------- Kernel 1: MFMA QKV projection ----------------
// Wave = 16 tokens x 192 cols (wpart = wid&1; row-tile = gw>>1).
// v: MFMA C-layout is t-contiguous per lane -> packed b64 direct stores.
// q/k: per-wave LDS stage [t][col] (padded), flushed as coalesced 16B stores.
__global__ __launch_bounds__(256) void qkv_mfma(
    const float* __restrict__ x, const ushort_t* __restrict__ Wt,
    __hip_bfloat16* __restrict__ qws, __hip_bfloat16* __restrict__ kws,
    __hip_bfloat16* __restrict__ vtws)
{
    __shared__ ushort_t qkA[2][16 * 200]; // wid 0,2: q(128)+k(0..63) cols
    __shared__ ushort_t qkB[2][16 * 72];  // wid 1,3: k(64..127) cols

    const int tid = threadIdx.x;
    const int lane = tid & 63;
    const int i15 = lane & 15, quad = lane >> 4;
    const int wid = tid >> 6;
    const int wpart = wid & 1;
    const int pairIdx = wid >> 1;
    const int gw = blockIdx.x * 4 + wid;
    const int row0 = (gw >> 1) * 16;
    const int b = row0 >> 10, t0 = row0 & 1023;

    // A-frags: x rows (f32 -> bf16 in-register)
    short8_t af[4];
    #pragma unroll
    for (int kc = 0; kc < 4; ++kc) {
        const float4 x0 = *(const float4*)(x + (size_t)(row0 + i15) * 128 + kc * 32 + quad * 8);
        const float4 x1 = *(const float4*)(x + (size_t)(row0 + i15) * 128 + kc * 32 + quad * 8 + 4);
        short8_t a;
        a[0] = (short)f2bf_bits(x0.x); a[1] = (short)f2bf_bits(x0.y);
        a[2] = (short)f2bf_bits(x0.z); a[3] = (short)f2bf_bits(x0.w);
        a[4] = (short)f2bf_bits(x1.x); a[5] = (short)f2bf_bits(x1.y);
        a[6] = (short)f2bf_bits(x1.z); a[7] = (short)f2bf_bits(x1.w);
        af[kc] = a;
    }

    float4_t acc[12];
    #pragma unroll
    for (int nt = 0; nt < 12; ++nt) acc[nt] = (float4_t){0.f, 0.f, 0.f, 0.f};

    #pragma unroll
    for (int nt = 0; nt < 12; ++nt) {
        const int n = wpart * 192 + nt * 16 + i15;
        const ushort_t* wb = Wt + (size_t)n * 128 + quad * 8;
        #pragma unroll
        for (int kc = 0; kc < 4; ++kc) {
            const short8_t bf = *(const short8_t*)(wb + kc * 32);
            acc[nt] = __builtin_amdgcn_mfma_f32_16x16x32_bf16(af[kc], bf, acc[nt], 0, 0, 0);
        }
    }

    const float scale = 0.17677669529663687f; // 1/sqrt(32)

    if (wpart == 0) {
        // cols 0..191 = q ch 0..127 (scaled), k ch 0..63
        ushort_t* Ls = qkA[pairIdx];
        #pragma unroll
        for (int nt = 0; nt < 12; ++nt) {
            const int col = nt * 16 + i15;
            const float sc = (nt < 8) ? scale : 1.f;
            #pragma unroll
            for (int r = 0; r < 4; ++r)
                Ls[(quad * 4 + r) * 200 + col] = f2bf_bits(acc[nt][r] * sc);
        }
        // flush: it 0..3 -> q heads 0..3; it 4,5 -> k heads 0,1
        const int t = lane >> 2, c4 = lane & 3;
        #pragma unroll
        for (int it = 0; it < 6; ++it) {
            const int col8 = it * 4 + c4;
            const ushort8_t v8 = *(const ushort8_t*)(Ls + t * 200 + col8 * 8);
            __hip_bfloat16* base = (it < 4) ? qws : kws;
            const int h = (it < 4) ? it : (it - 4);
            *(ushort8_t*)((ushort_t*)base +
                ((size_t)(b * H_ + h) * T_ + t0 + t) * DH_ + c4 * 8) = v8;
        }
    } else {
        // cols 192..383 = k ch 64..127 (nt 0..3), v ch 0..127 (nt 4..11)
        ushort_t* Ls = qkB[pairIdx];
        #pragma unroll
        for (int nt = 0; nt < 12; ++nt) {
            if (nt < 4) {
                const int col = nt * 16 + i15; // k ch 64+col
                #pragma unroll
                for (int r = 0; r < 4; ++r)
                    Ls[(quad * 4 + r) * 72 + col] = f2bf_bits(acc[nt][r]);
            } else {
                const int ch = nt * 16 + i15 - 64; // v channel 0..127
                const int h = ch >> 5, dh = ch & 31;
                ushort4_t pk;
                #pragma unroll
                for (int r = 0; r < 4; ++r) pk[r] = f2bf_bits(acc[nt][r]);
                *(ushort4_t*)((ushort_t*)vtws +
                    ((size_t)(b * H_ + h) * DH_ + dh) * T_ + t0 + quad * 4) = pk;
            }
        }
        // flush k heads 2,3
        const int t = lane >> 2, c4 = lane & 3;
        #pragma unroll
        for (int it = 0; it < 2; ++it) {
            const int col8 = it * 4 + c4;
            const ushort8_t v8 = *(const ushort8_t*)(Ls + t * 72 + col8 * 8);
            *(ushort8_t*)((ushort_t*)kws +
                ((size_t)(b * H_ + 2 + it) * T_ + t0 + t) * DH_ + c4 * 8) = v8;
        }
    }
}

// ---------------- Kernel 2: split-K MFMA flash attention ----------------
// Block per (bh, 16-query tile); wave w takes chunks c = w, w+4, ...
// Fast path for mask-free chunks; P packed by truncation (1 inst).
__global__ __launch_bounds__(256) void attn_mfma(
    const ushort_t* __restrict__ qws, const ushort_t* __restrict__ kws,
    const ushort_t* __restrict__ vtws, const int* __restrict__ keys_length,
    __hip_bfloat16* __restrict__ attn_out)
{
    __shared__ float smem[2304];

    const int wid = threadIdx.x >> 6;
    const int lane = threadIdx.x & 63;
    const int i15 = lane & 15, quad = lane >> 4;
    const int g = blockIdx.x & 63;
    const int bh = blockIdx.x >> 6;
    const int b = bh >> 2, h = bh & 3;
    const int qt = 63 - g;            // heavy tiles first
    const int qbase = qt * 16;
    const int len = keys_length[b];

    const ushort_t* Qb = qws + (size_t)bh * T_ * DH_;
    const ushort_t* Kb = kws + (size_t)bh * T_ * DH_;
    const ushort_t* Vtb = vtws + (size_t)bh * DH_ * T_;

    const short8_t qfrag =
        *(const short8_t*)(Qb + ((size_t)(qbase + i15)) * DH_ + quad * 8);

    int limit[4];
    #pragma unroll
    for (int r = 0; r < 4; ++r)
        limit[r] = min(qbase + quad * 4 + r + 1, len);

    const int kend = min(qbase + 16, len);
    const int nch = (kend + 63) >> 6;          // 64-key chunks, 1..16
    const int nfullc = min(qbase + 1, len) >> 6; // chunks needing no mask

    ushort_t* plds = (ushort_t*)(smem + wid * 576);

    float4_t o0 = {0.f, 0.f, 0.f, 0.f}, o1 = {0.f, 0.f, 0.f, 0.f};
    float lrow[4] = {0.f, 0.f, 0.f, 0.f};
    const float4_t zero = {0.f, 0.f, 0.f, 0.f};

    for (int c = wid; c < nch; c += 4) {
        const int k0 = c * 64;

        short8_t kf[4], vf[4];
        #pragma unroll
        for (int grp = 0; grp < 4; ++grp)
            kf[grp] = *(const short8_t*)(Kb + ((size_t)(k0 + grp * 16 + i15)) * DH_ + quad * 8);
        vf[0] = *(const short8_t*)(Vtb + (size_t)i15 * T_ + k0 + quad * 8);
        vf[1] = *(const short8_t*)(Vtb + (size_t)i15 * T_ + k0 + 32 + quad * 8);
        vf[2] = *(const short8_t*)(Vtb + (size_t)(16 + i15) * T_ + k0 + quad * 8);
        vf[3] = *(const short8_t*)(Vtb + (size_t)(16 + i15) * T_ + k0 + 32 + quad * 8);

        float4_t s[4];
        #pragma unroll
        for (int grp = 0; grp < 4; ++grp)
            s[grp] = __builtin_amdgcn_mfma_f32_16x16x32_bf16(qfrag, kf[grp], zero, 0, 0, 0);

        if (c < nfullc) { // no masking needed (wave-uniform branch)
            #pragma unroll
            for (int grp = 0; grp < 4; ++grp) {
                #pragma unroll
                for (int r = 0; r < 4; ++r) {
                    const float p = __expf(s[grp][r]);
                    lrow[r] += p;
                    plds[(quad * 4 + r) * 72 + grp * 16 + i15] = f2bf_trunc(p);
                }
            }
        } else {
            #pragma unroll
            for (int grp = 0; grp < 4; ++grp) {
                #pragma unroll
                for (int r = 0; r < 4; ++r) {
                    const float p = (k0 + grp * 16 + i15 < limit[r]) ? __expf(s[grp][r]) : 0.f;
                    lrow[r] += p;
                    plds[(quad * 4 + r) * 72 + grp * 16 + i15] = f2bf_trunc(p);
                }
            }
        }

        const short8_t pfA = *(const short8_t*)(plds + i15 * 72 + quad * 8);
        const short8_t pfB = *(const short8_t*)(plds + i15 * 72 + 32 + quad * 8);

        o0 = __builtin_amdgcn_mfma_f32_16x16x32_bf16(pfA, vf[0], o0, 0, 0, 0);
        o0 = __builtin_amdgcn_mfma_f32_16x16x32_bf16(pfB, vf[1], o0, 0, 0, 0);
        o1 = __builtin_amdgcn_mfma_f32_16x16x32_bf16(pfA, vf[2], o1, 0, 0, 0);
        o1 = __builtin_amdgcn_mfma_f32_16x16x32_bf16(pfB, vf[3], o1, 0, 0, 0);
    }

    #pragma unroll
    for (int r = 0; r < 4; ++r) {
        float s = lrow[r];
        #pragma unroll
        for (int off = 1; off < 16; off <<= 1)
            s += __shfl_xor(s, off, 64);
        lrow[r] = s;
    }

    __syncthreads(); // P-tile use done; smem becomes combine buffer

    float* comb = smem + wid * 576;
    #pragma unroll
    for (int r = 0; r < 4; ++r) {
        comb[(quad * 4 + r) * 32 + i15] = o0[r];
        comb[(quad * 4 + r) * 32 + 16 + i15] = o1[r];
    }
    if (i15 == 0) {
        #pragma unroll
        for (int r = 0; r < 4; ++r)
            comb[512 + quad * 4 + r] = lrow[r];
    }
    __syncthreads();

    #pragma unroll
    for (int e = threadIdx.x; e < 512; e += 256) {
        const int row = e >> 5, col = e & 31;
        const float osum = smem[e] + smem[576 + e] + smem[1152 + e] + smem[1728 + e];
        const float lsum = smem[512 + row] + smem[1088 + row] +
                           smem[1664 + row] + smem[2240 + row];
        attn_out[((size_t)b * T_ + qbase + row) * D_ + h * DH_ + col] =
            __float2bfloat16(osum / lsum);
    }
}

// ---------------- Kernel 3: MFMA output proj + residual + LN ----------------
// One wave per block (2048 blocks) for better spread; 32 MFMAs; in-wave LN.
__global__ __launch_bounds__(64) void proj_ln_mfma(
    const ushort_t* __restrict__ attn, const float* __restrict__ x,
    const ushort_t* __restrict__ Wot, const float* __restrict__ gamma,
    const float* __restrict__ beta, float* __restrict__ out)
{
    const int lane = threadIdx.x;
    const int i15 = lane & 15, quad = lane >> 4;
    const int row0 = blockIdx.x * 16;

    short8_t af[4];
    #pragma unroll
    for (int kc = 0; kc < 4; ++kc)
        af[kc] = *(const short8_t*)(attn + (size_t)(row0 + i15) * 128 + kc * 32 + quad * 8);

    float4_t acc[8];
    #pragma unroll
    for (int nt = 0; nt < 8; ++nt) acc[nt] = (float4_t){0.f, 0.f, 0.f, 0.f};

    #pragma unroll
    for (int nt = 0; nt < 8; ++nt) {
        const ushort_t* wb = Wot + (size_t)(nt * 16 + i15) * 128 + quad * 8;
        #pragma unroll
        for (int kc = 0; kc < 4; ++kc) {
            const short8_t bf = *(const short8_t*)(wb + kc * 32);
            acc[nt] = __builtin_amdgcn_mfma_f32_16x16x32_bf16(af[kc], bf, acc[nt], 0, 0, 0);
        }
    }

    float g[8], be[8];
    #pragma unroll
    for (int nt = 0; nt < 8; ++nt) {
        g[nt] = gamma[nt * 16 + i15];
        be[nt] = beta[nt * 16 + i15];
    }

    #pragma unroll
    for (int r = 0; r < 4; ++r) {
        const int m = row0 + quad * 4 + r;
        float y[8];
        float s1 = 0.f, s2 = 0.f;
        #pragma unroll
        for (int nt = 0; nt < 8; ++nt) {
            y[nt] = acc[nt][r] + x[(size_t)m * 128 + nt * 16 + i15];
            s1 += y[nt];
            s2 += y[nt] * y[nt];
        }
        #pragma unroll
        for (int off = 1; off < 16; off <<= 1) {
            s1 += __shfl_xor(s1, off, 64);
            s2 += __shfl_xor(s2, off, 64);
        }
        const float mean = s1 * (1.f / 128.f);
        const float var = s2 * (1.f / 128.f) - mean * mean;
        const float rstd = rsqrtf(var + 1e-9f);
        #pragma unroll
        for (int nt = 0; nt < 8; ++nt)
            out[(size_t)m * 128 + nt * 16 + i15] = (y[nt] - mean) * rstd * g[nt] + be[nt];
    }
}

extern "C" void kernel_launch(void* const* d_in, const int* in_sizes, int n_in,
                              void* d_out, int out_size, void* d_ws, size_t ws_size,
                              hipStream_t stream) {
    const float* x      = (const float*)d_in[0];
    const int* keys_len = (const int*)d_in[1];
    const float* W      = (const float*)d_in[2];
    const float* Wo     = (const float*)d_in[3];
    const float* gamma  = (const float*)d_in[4];
    const float* beta   = (const float*)d_in[5];
    float* out          = (float*)d_out;  // f32 output (proven round 5)

    // ws (32 MB, proven): q | k | vt | attn-out segments, 8 MB each.
    // Wt lives in attn-out segment (dead until attn); Wot in q segment
    // (dead after attn).
    const size_t seg = (size_t)B_ * H_ * T_ * DH_;
    __hip_bfloat16* qws  = (__hip_bfloat16*)d_ws;
    __hip_bfloat16* kws  = qws + seg;
    __hip_bfloat16* vtws = qws + 2 * seg;
    __hip_bfloat16* aws  = qws + 3 * seg;
    ushort_t* Wt  = (ushort_t*)aws;
    ushort_t* Wot = (ushort_t*)qws;

    transpose_w<<<192, 256, 0, stream>>>(W, Wt);
    qkv_mfma<<<B_ * T_ / 32, 256, 0, stream>>>(x, Wt, qws, kws, vtws);
    attn_mfma<<<B_ * H_ * (T_ / 16), 256, 0, stream>>>(
        (const ushort_t*)qws, (const ushort_t*)kws, (const ushort_t*)vtws,
        keys_len, aws);
    transpose_wo<<<64, 256, 0, stream>>>(Wo, Wot);
    proj_ln_mfma<<<B_ * T_ / 16, 64, 0, stream>>>(
        (const ushort_t*)aws, x, Wot, gamma, beta, out);
}

// Round 13
// 142.684 us; speedup vs baseline: 1.2187x; 1.1380x over previous
//
#include <hip/hip_runtime.h>
#include <hip/hip_bf16.h>

#define B_ 32
#define T_ 1024
#define D_ 128
#define H_ 4
#define DH_ 32

typedef unsigned short ushort_t;
typedef unsigned int uint_t;
typedef unsigned short ushort4_t __attribute__((ext_vector_type(4)));
typedef unsigned short ushort8_t __attribute__((ext_vector_type(8)));
typedef short short8_t __attribute__((ext_vector_type(8)));
typedef float float4_t __attribute__((ext_vector_type(4)));

__device__ __forceinline__ ushort_t f2bf_bits(float f) {
    __hip_bfloat16 h = __float2bfloat16(f);
    return *reinterpret_cast<ushort_t*>(&h);
}
// pack trunc-bf16(hi)<<16 | trunc-bf16(lo) in one v_perm_b32
__device__ __forceinline__ uint_t pk_bf16(float hi, float lo) {
    return __builtin_amdgcn_perm(__float_as_uint(hi), __float_as_uint(lo),
                                 0x07060302u);
}

// ---- tiny transpose kernels (bf16 B-frag layouts for MFMA) ----
__global__ __launch_bounds__(256) void transpose_w(
    const float* __restrict__ W, ushort_t* __restrict__ Wt)
{
    const int id = blockIdx.x * 256 + threadIdx.x;
    const int n = id >> 7, k = id & 127;
    Wt[id] = f2bf_bits(W[(size_t)k * 384 + n]);
}
__global__ __launch_bounds__(256) void transpose_wo(
    const float* __restrict__ Wo, ushort_t* __restrict__ Wot)
{
    const int id = blockIdx.x * 256 + threadIdx.x;
    const int n = id >> 7, k = id & 127;
    Wot[id] = f2bf_bits(Wo[(size_t)k * 128 + n]);
}

// ---------------- Kernel 1: MFMA QKV projection (round-12, passing) --------
__global__ __launch_bounds__(256) void qkv_mfma(
    const float* __restrict__ x, const ushort_t* __restrict__ Wt,
    __hip_bfloat16* __restrict__ qws, __hip_bfloat16* __restrict__ kws,
    __hip_bfloat16* __restrict__ vtws)
{
    __shared__ ushort_t qkA[2][16 * 200];
    __shared__ ushort_t qkB[2][16 * 72];

    const int tid = threadIdx.x;
    const int lane = tid & 63;
    const int i15 = lane & 15, quad = lane >> 4;
    const int wid = tid >> 6;
    const int wpart = wid & 1;
    const int pairIdx = wid >> 1;
    const int gw = blockIdx.x * 4 + wid;
    const int row0 = (gw >> 1) * 16;
    const int b = row0 >> 10, t0 = row0 & 1023;

    short8_t af[4];
    #pragma unroll
    for (int kc = 0; kc < 4; ++kc) {
        const float4 x0 = *(const float4*)(x + (size_t)(row0 + i15) * 128 + kc * 32 + quad * 8);
        const float4 x1 = *(const float4*)(x + (size_t)(row0 + i15) * 128 + kc * 32 + quad * 8 + 4);
        short8_t a;
        a[0] = (short)f2bf_bits(x0.x); a[1] = (short)f2bf_bits(x0.y);
        a[2] = (short)f2bf_bits(x0.z); a[3] = (short)f2bf_bits(x0.w);
        a[4] = (short)f2bf_bits(x1.x); a[5] = (short)f2bf_bits(x1.y);
        a[6] = (short)f2bf_bits(x1.z); a[7] = (short)f2bf_bits(x1.w);
        af[kc] = a;
    }

    float4_t acc[12];
    #pragma unroll
    for (int nt = 0; nt < 12; ++nt) acc[nt] = (float4_t){0.f, 0.f, 0.f, 0.f};

    #pragma unroll
    for (int nt = 0; nt < 12; ++nt) {
        const int n = wpart * 192 + nt * 16 + i15;
        const ushort_t* wb = Wt + (size_t)n * 128 + quad * 8;
        #pragma unroll
        for (int kc = 0; kc < 4; ++kc) {
            const short8_t bf = *(const short8_t*)(wb + kc * 32);
            acc[nt] = __builtin_amdgcn_mfma_f32_16x16x32_bf16(af[kc], bf, acc[nt], 0, 0, 0);
        }
    }

    const float scale = 0.17677669529663687f; // 1/sqrt(32)

    if (wpart == 0) {
        ushort_t* Ls = qkA[pairIdx];
        #pragma unroll
        for (int nt = 0; nt < 12; ++nt) {
            const int col = nt * 16 + i15;
            const float sc = (nt < 8) ? scale : 1.f;
            #pragma unroll
            for (int r = 0; r < 4; ++r)
                Ls[(quad * 4 + r) * 200 + col] = f2bf_bits(acc[nt][r] * sc);
        }
        const int t = lane >> 2, c4 = lane & 3;
        #pragma unroll
        for (int it = 0; it < 6; ++it) {
            const int col8 = it * 4 + c4;
            const ushort8_t v8 = *(const ushort8_t*)(Ls + t * 200 + col8 * 8);
            __hip_bfloat16* base = (it < 4) ? qws : kws;
            const int h = (it < 4) ? it : (it - 4);
            *(ushort8_t*)((ushort_t*)base +
                ((size_t)(b * H_ + h) * T_ + t0 + t) * DH_ + c4 * 8) = v8;
        }
    } else {
        ushort_t* Ls = qkB[pairIdx];
        #pragma unroll
        for (int nt = 0; nt < 12; ++nt) {
            if (nt < 4) {
                const int col = nt * 16 + i15;
                #pragma unroll
                for (int r = 0; r < 4; ++r)
                    Ls[(quad * 4 + r) * 72 + col] = f2bf_bits(acc[nt][r]);
            } else {
                const int ch = nt * 16 + i15 - 64;
                const int h = ch >> 5, dh = ch & 31;
                ushort4_t pk;
                #pragma unroll
                for (int r = 0; r < 4; ++r) pk[r] = f2bf_bits(acc[nt][r]);
                *(ushort4_t*)((ushort_t*)vtws +
                    ((size_t)(b * H_ + h) * DH_ + dh) * T_ + t0 + quad * 4) = pk;
            }
        }
        const int t = lane >> 2, c4 = lane & 3;
        #pragma unroll
        for (int it = 0; it < 2; ++it) {
            const int col8 = it * 4 + c4;
            const ushort8_t v8 = *(const ushort8_t*)(Ls + t * 72 + col8 * 8);
            *(ushort8_t*)((ushort_t*)kws +
                ((size_t)(b * H_ + 2 + it) * T_ + t0 + t) * DH_ + c4 * 8) = v8;
        }
    }
}

// ---------------- Kernel 2: 32q-strip split-K MFMA flash attention ---------
// Block = (bh, 32-query strip), 2 waves; wave w takes 64-key chunks c ≡ w (2).
// S^T MFMA (A=K, B=Q): P rows are key-contiguous per lane -> b64 packed LDS
// writes; per-lane causal limit (q = i15). Both subtiles share kf/vf frags.
__global__ __launch_bounds__(128) void attn_mfma(
    const ushort_t* __restrict__ qws, const ushort_t* __restrict__ kws,
    const ushort_t* __restrict__ vtws, const int* __restrict__ keys_length,
    __hip_bfloat16* __restrict__ attn_out)
{
    __shared__ ushort_t plds_all[2][32 * 72]; // 9216 B; comb overlays wave0 part

    const int wid = threadIdx.x >> 6;
    const int lane = threadIdx.x & 63;
    const int i15 = lane & 15, quad = lane >> 4;
    const int bh = blockIdx.x & 127;          // strip-major: global heavy-first
    const int st = 31 - (blockIdx.x >> 7);
    const int qbase = st * 32;
    const int b = bh >> 2, h = bh & 3;
    const int len = keys_length[b];

    const ushort_t* Qb = qws + (size_t)bh * T_ * DH_;
    const ushort_t* Kb = kws + (size_t)bh * T_ * DH_;
    const ushort_t* Vtb = vtws + (size_t)bh * DH_ * T_;

    const short8_t qfA = *(const short8_t*)(Qb + (size_t)(qbase + i15) * DH_ + quad * 8);
    const short8_t qfB = *(const short8_t*)(Qb + (size_t)(qbase + 16 + i15) * DH_ + quad * 8);

    const int kend    = min(qbase + 32, len);
    const int nch     = (kend + 63) >> 6;       // 1..16
    const int limAmax = min(qbase + 16, len);
    const int nfullA  = min(qbase + 1, len) >> 6;
    const int nfullB  = min(qbase + 17, len) >> 6;
    const int limA    = min(qbase + i15 + 1, len);      // per-lane: q = i15
    const int limB    = min(qbase + 16 + i15 + 1, len);

    ushort_t* pl = plds_all[wid];

    float4_t oA0 = {0,0,0,0}, oA1 = {0,0,0,0}, oB0 = {0,0,0,0}, oB1 = {0,0,0,0};
    float laccA = 0.f, laccB = 0.f;
    const float4_t zero = {0,0,0,0};

    for (int c = wid; c < nch; c += 2) {
        const int k0 = c * 64;
        const bool doA = (k0 < limAmax);        // wave-uniform

        short8_t kf[4], vf[4];
        #pragma unroll
        for (int g = 0; g < 4; ++g)
            kf[g] = *(const short8_t*)(Kb + (size_t)(k0 + g * 16 + i15) * DH_ + quad * 8);
        vf[0] = *(const short8_t*)(Vtb + (size_t)i15 * T_ + k0 + quad * 8);
        vf[1] = *(const short8_t*)(Vtb + (size_t)i15 * T_ + k0 + 32 + quad * 8);
        vf[2] = *(const short8_t*)(Vtb + (size_t)(16 + i15) * T_ + k0 + quad * 8);
        vf[3] = *(const short8_t*)(Vtb + (size_t)(16 + i15) * T_ + k0 + 32 + quad * 8);

        // QK^T transposed: D[key][q]
        float4_t sB[4], sA[4];
        #pragma unroll
        for (int g = 0; g < 4; ++g)
            sB[g] = __builtin_amdgcn_mfma_f32_16x16x32_bf16(kf[g], qfB, zero, 0, 0, 0);
        if (doA) {
            #pragma unroll
            for (int g = 0; g < 4; ++g)
                sA[g] = __builtin_amdgcn_mfma_f32_16x16x32_bf16(kf[g], qfA, zero, 0, 0, 0);
        }

        // exp + pack + LDS (subtile B -> rows 16..31)
        {
            const bool fullB = (c < nfullB);
            ushort_t* prow = pl + (16 + i15) * 72 + quad * 4;
            #pragma unroll
            for (int g = 0; g < 4; ++g) {
                float p0 = __expf(sB[g][0]), p1 = __expf(sB[g][1]);
                float p2 = __expf(sB[g][2]), p3 = __expf(sB[g][3]);
                if (!fullB) {
                    const int d = limB - (k0 + g * 16 + quad * 4);
                    p0 = (d > 0) ? p0 : 0.f; p1 = (d > 1) ? p1 : 0.f;
                    p2 = (d > 2) ? p2 : 0.f; p3 = (d > 3) ? p3 : 0.f;
                }
                laccB += (p0 + p1) + (p2 + p3);
                uint2 w; w.x = pk_bf16(p1, p0); w.y = pk_bf16(p3, p2);
                *(uint2*)(prow + g * 16) = w;
            }
        }
        if (doA) { // subtile A -> rows 0..15
            const bool fullA = (c < nfullA);
            ushort_t* prow = pl + i15 * 72 + quad * 4;
            #pragma unroll
            for (int g = 0; g < 4; ++g) {
                float p0 = __expf(sA[g][0]), p1 = __expf(sA[g][1]);
                float p2 = __expf(sA[g][2]), p3 = __expf(sA[g][3]);
                if (!fullA) {
                    const int d = limA - (k0 + g * 16 + quad * 4);
                    p0 = (d > 0) ? p0 : 0.f; p1 = (d > 1) ? p1 : 0.f;
                    p2 = (d > 2) ? p2 : 0.f; p3 = (d > 3) ? p3 : 0.f;
                }
                laccA += (p0 + p1) + (p2 + p3);
                uint2 w; w.x = pk_bf16(p1, p0); w.y = pk_bf16(p3, p2);
                *(uint2*)(prow + g * 16) = w;
            }
        }

        // PV (shared vf frags)
        {
            const short8_t pfB0 = *(const short8_t*)(pl + (16 + i15) * 72 + quad * 8);
            const short8_t pfB1 = *(const short8_t*)(pl + (16 + i15) * 72 + 32 + quad * 8);
            oB0 = __builtin_amdgcn_mfma_f32_16x16x32_bf16(pfB0, vf[0], oB0, 0, 0, 0);
            oB0 = __builtin_amdgcn_mfma_f32_16x16x32_bf16(pfB1, vf[1], oB0, 0, 0, 0);
            oB1 = __builtin_amdgcn_mfma_f32_16x16x32_bf16(pfB0, vf[2], oB1, 0, 0, 0);
            oB1 = __builtin_amdgcn_mfma_f32_16x16x32_bf16(pfB1, vf[3], oB1, 0, 0, 0);
        }
        if (doA) {
            const short8_t pfA0 = *(const short8_t*)(pl + i15 * 72 + quad * 8);
            const short8_t pfA1 = *(const short8_t*)(pl + i15 * 72 + 32 + quad * 8);
            oA0 = __builtin_amdgcn_mfma_f32_16x16x32_bf16(pfA0, vf[0], oA0, 0, 0, 0);
            oA0 = __builtin_amdgcn_mfma_f32_16x16x32_bf16(pfA1, vf[1], oA0, 0, 0, 0);
            oA1 = __builtin_amdgcn_mfma_f32_16x16x32_bf16(pfA0, vf[2], oA1, 0, 0, 0);
            oA1 = __builtin_amdgcn_mfma_f32_16x16x32_bf16(pfA1, vf[3], oA1, 0, 0, 0);
        }
    }

    // l partial: sum across the 4 quads (per q = i15)
    laccA += __shfl_xor(laccA, 16, 64); laccA += __shfl_xor(laccA, 32, 64);
    laccB += __shfl_xor(laccB, 16, 64); laccB += __shfl_xor(laccB, 32, 64);

    float* comb = (float*)(&plds_all[0][0]); // 1024 o + 32 l floats (<= wave0 tile)
    if (wid == 0) {
        #pragma unroll
        for (int r = 0; r < 4; ++r) {
            const int q = quad * 4 + r;
            comb[q * 32 + i15] = oA0[r];
            comb[q * 32 + 16 + i15] = oA1[r];
            comb[(16 + q) * 32 + i15] = oB0[r];
            comb[(16 + q) * 32 + 16 + i15] = oB1[r];
        }
        if (quad == 0) { comb[1024 + i15] = laccA; comb[1024 + 16 + i15] = laccB; }
    }
    __syncthreads();
    if (wid == 1) {
        const float lAq = laccA + comb[1024 + i15];
        const float lBq = laccB + comb[1024 + 16 + i15];
        #pragma unroll
        for (int r = 0; r < 4; ++r) {
            const int q = quad * 4 + r;
            const float invA = 1.f / __shfl(lAq, q, 64);
            const float invB = 1.f / __shfl(lBq, q, 64);
            const float a0 = oA0[r] + comb[q * 32 + i15];
            const float a1 = oA1[r] + comb[q * 32 + 16 + i15];
            const float b0 = oB0[r] + comb[(16 + q) * 32 + i15];
            const float b1 = oB1[r] + comb[(16 + q) * 32 + 16 + i15];
            const size_t baseA = ((size_t)b * T_ + qbase + q) * D_ + h * DH_;
            const size_t baseB = ((size_t)b * T_ + qbase + 16 + q) * D_ + h * DH_;
            attn_out[baseA + i15] = __float2bfloat16(a0 * invA);
            attn_out[baseA + 16 + i15] = __float2bfloat16(a1 * invA);
            attn_out[baseB + i15] = __float2bfloat16(b0 * invB);
            attn_out[baseB + 16 + i15] = __float2bfloat16(b1 * invB);
        }
    }
}

// ---------------- Kernel 3: MFMA output proj + residual + LN (round-12) ----
__global__ __launch_bounds__(64) void proj_ln_mfma(
    const ushort_t* __restrict__ attn, const float* __restrict__ x,
    const ushort_t* __restrict__ Wot, const float* __restrict__ gamma,
    const float* __restrict__ beta, float* __restrict__ out)
{
    const int lane = threadIdx.x;
    const int i15 = lane & 15, quad = lane >> 4;
    const int row0 = blockIdx.x * 16;

    short8_t af[4];
    #pragma unroll
    for (int kc = 0; kc < 4; ++kc)
        af[kc] = *(const short8_t*)(attn + (size_t)(row0 + i15) * 128 + kc * 32 + quad * 8);

    float4_t acc[8];
    #pragma unroll
    for (int nt = 0; nt < 8; ++nt) acc[nt] = (float4_t){0.f, 0.f, 0.f, 0.f};

    #pragma unroll
    for (int nt = 0; nt < 8; ++nt) {
        const ushort_t* wb = Wot + (size_t)(nt * 16 + i15) * 128 + quad * 8;
        #pragma unroll
        for (int kc = 0; kc < 4; ++kc) {
            const short8_t bf = *(const short8_t*)(wb + kc * 32);
            acc[nt] = __builtin_amdgcn_mfma_f32_16x16x32_bf16(af[kc], bf, acc[nt], 0, 0, 0);
        }
    }

    float g[8], be[8];
    #pragma unroll
    for (int nt = 0; nt < 8; ++nt) {
        g[nt] = gamma[nt * 16 + i15];
        be[nt] = beta[nt * 16 + i15];
    }

    #pragma unroll
    for (int r = 0; r < 4; ++r) {
        const int m = row0 + quad * 4 + r;
        float y[8];
        float s1 = 0.f, s2 = 0.f;
        #pragma unroll
        for (int nt = 0; nt < 8; ++nt) {
            y[nt] = acc[nt][r] + x[(size_t)m * 128 + nt * 16 + i15];
            s1 += y[nt];
            s2 += y[nt] * y[nt];
        }
        #pragma unroll
        for (int off = 1; off < 16; off <<= 1) {
            s1 += __shfl_xor(s1, off, 64);
            s2 += __shfl_xor(s2, off, 64);
        }
        const float mean = s1 * (1.f / 128.f);
        const float var = s2 * (1.f / 128.f) - mean * mean;
        const float rstd = rsqrtf(var + 1e-9f);
        #pragma unroll
        for (int nt = 0; nt < 8; ++nt)
            out[(size_t)m * 128 + nt * 16 + i15] = (y[nt] - mean) * rstd * g[nt] + be[nt];
    }
}

extern "C" void kernel_launch(void* const* d_in, const int* in_sizes, int n_in,
                              void* d_out, int out_size, void* d_ws, size_t ws_size,
                              hipStream_t stream) {
    const float* x      = (const float*)d_in[0];
    const int* keys_len = (const int*)d_in[1];
    const float* W      = (const float*)d_in[2];
    const float* Wo     = (const float*)d_in[3];
    const float* gamma  = (const float*)d_in[4];
    const float* beta   = (const float*)d_in[5];
    float* out          = (float*)d_out;  // f32 output (proven round 5)

    // ws (32 MB, proven): q | k | vt | attn-out segments, 8 MB each.
    // Wt lives in attn-out segment (dead until attn); Wot in q segment
    // (dead after attn).
    const size_t seg = (size_t)B_ * H_ * T_ * DH_;
    __hip_bfloat16* qws  = (__hip_bfloat16*)d_ws;
    __hip_bfloat16* kws  = qws + seg;
    __hip_bfloat16* vtws = qws + 2 * seg;
    __hip_bfloat16* aws  = qws + 3 * seg;
    ushort_t* Wt  = (ushort_t*)aws;
    ushort_t* Wot = (ushort_t*)qws;

    transpose_w<<<192, 256, 0, stream>>>(W, Wt);
    qkv_mfma<<<B_ * T_ / 32, 256, 0, stream>>>(x, Wt, qws, kws, vtws);
    // 128 bh x 32 strips; strip-major so heaviest strips dispatch first
    attn_mfma<<<B_ * H_ * (T_ / 32), 128, 0, stream>>>(
        (const ushort_t*)qws, (const ushort_t*)kws, (const ushort_t*)vtws,
        keys_len, aws);
    transpose_wo<<<64, 256, 0, stream>>>(Wo, Wot);
    proj_ln_mfma<<<B_ * T_ / 16, 64, 0, stream>>>(
        (const ushort_t*)aws, x, Wot, gamma, beta, out);
}